// Round 6
// baseline (206.409 us; speedup 1.0000x reference)
//
#include <hip/hip_runtime.h>
#include <math.h>

// Conv-KNRM on MI355X. B=128, QLEN=30, DLEN=256, EMB=300 (pad 320), C=128.
//
// Pipeline:
//   prep_w   : w fp32 [C,E,k] -> wt2 bf16 fragment-order
//              [plane(6)][cb(8)][ec(10)][lane(64)][8]
//   conv_all : fused 3-gram conv, SWAPPED operands: A=w (ch -> quad*4+reg),
//              B=x rows (l -> lane&15). As stride 344 (2-way-free b128).
//              Epilogue: register ssq + 2 shfls + dwordx2 packed stores.
//              -> bf16 [g][b][l][c]
//   pool_mfma: LDS-free MFMA cos, 32-d chunks (3072 waves), RBF x11 -> pkq8
//   final    : sum 8 chunks, log/clip/qmask/sum_q dot dense_w -> out[128]
//
// ws: wt2 bf16 245760 | qn bf16 1474560 | dn bf16 12582912 | pkq8 f32 3041280

typedef __bf16 bf16x8 __attribute__((ext_vector_type(8)));
typedef float f32x4 __attribute__((ext_vector_type(4)));

#if __has_builtin(__builtin_amdgcn_exp2f)
#define EXP2F(x) __builtin_amdgcn_exp2f(x)
#else
#define EXP2F(x) exp2f(x)
#endif

#define AS_STRIDE 344  // shorts; 688 B/row: bank stride 12 -> 2-way (free), 16B-aligned

static __device__ __forceinline__ unsigned short f2bf(float f) {
  union { float f; unsigned int u; } v; v.f = f;
  unsigned int r = v.u + 0x7FFFu + ((v.u >> 16) & 1u);  // RNE
  return (unsigned short)(r >> 16);
}

__global__ __launch_bounds__(256) void prep_w(
    const float* __restrict__ w1, const float* __restrict__ w2,
    const float* __restrict__ w3, unsigned short* __restrict__ wt2) {
  int idx = blockIdx.x * 256 + threadIdx.x;
  if (idx >= 245760) return;
  int jj   = idx & 7;
  int lane = (idx >> 3) & 63;
  int ec   = (idx >> 9) % 10;
  int cb   = (idx / 5120) & 7;
  int p    = idx / 40960;
  const float* w; int k, jt;
  if (p == 0)      { w = w1; k = 1; jt = 0; }
  else if (p <= 2) { w = w2; k = 2; jt = p - 1; }
  else             { w = w3; k = 3; jt = p - 3; }
  int c = cb * 16 + (lane & 15);
  int e = ec * 32 + (lane >> 4) * 8 + jj;
  float v = (e < 300) ? w[(c * 300 + e) * k + jt] : 0.0f;
  wt2[idx] = f2bf(v);
}

__device__ __forceinline__ constexpr int bIndex(int nt, int j) {
  constexpr int base[6] = {0, 1, 2, 4, 6, 9};
  return base[nt] + j;
}

// Wave tile: NI*16 l-rows x 96 ch (6 ch-tiles: nt>>1 = gram, ch-base
// ((nt&1)*4+w)*16). A-operand = weights (frag-order global), B = x from LDS.
// D: ch = quad*4+reg, l = ni*16+lrow.
template<int NI>
__device__ __forceinline__ void conv_body(
    unsigned short* As, float (*ssq)[64],
    const float* __restrict__ x, int L, int l0, int b,
    const unsigned short* __restrict__ wt2,
    const float* __restrict__ b1, const float* __restrict__ b2,
    const float* __restrict__ b3,
    unsigned short* __restrict__ out) {
  constexpr int ROWS = NI * 16 + 2;
  const int t = threadIdx.x;
  const int w = __builtin_amdgcn_readfirstlane(t >> 6);
  const int lane = t & 63;
  const int quad = lane >> 4, lrow = lane & 15;

  if (t < 192) ssq[t >> 6][t & 63] = 0.0f;

  // stage A once: fp32 -> bf16, rows l0..l0+ROWS-1, e 0..319 (zero pad)
  const float* xb = x + (size_t)b * L * 300;
  for (int idx = t; idx < ROWS * 80; idx += 256) {
    int r = idx / 80, e4 = idx % 80;
    int e = e4 * 4;
    int l = l0 + r;
    float4 v = make_float4(0.f, 0.f, 0.f, 0.f);
    if (l < L && e < 300) v = *reinterpret_cast<const float4*>(xb + l * 300 + e);
    unsigned int lo = (unsigned int)f2bf(v.x) | ((unsigned int)f2bf(v.y) << 16);
    unsigned int hi = (unsigned int)f2bf(v.z) | ((unsigned int)f2bf(v.w) << 16);
    *reinterpret_cast<uint2*>(&As[r * AS_STRIDE + e]) = make_uint2(lo, hi);
  }
  __syncthreads();

  f32x4 acc[NI][6];
  #pragma unroll
  for (int ni = 0; ni < NI; ++ni)
    #pragma unroll
    for (int nt = 0; nt < 6; ++nt) acc[ni][nt] = (f32x4){0.f, 0.f, 0.f, 0.f};

  const unsigned short* wl = wt2 + lane * 8;

  #pragma unroll 2
  for (int ec = 0; ec < 10; ++ec) {
    bf16x8 wf[12];
    #pragma unroll
    for (int nt = 0; nt < 6; ++nt) {
      const int g = nt >> 1;
      const int cb = (nt & 1) * 4 + w;
      const int pst = (g * (g + 1)) >> 1;
      #pragma unroll
      for (int j = 0; j <= g; ++j)
        wf[bIndex(nt, j)] = *reinterpret_cast<const bf16x8*>(
            wl + ((((pst + j) * 8 + cb) * 10 + ec) << 9));
    }
    #pragma unroll
    for (int j = 0; j < 3; ++j) {
      bf16x8 xf[NI];
      #pragma unroll
      for (int ni = 0; ni < NI; ++ni)
        xf[ni] = *reinterpret_cast<const bf16x8*>(
            &As[(ni * 16 + lrow + j) * AS_STRIDE + ec * 32 + quad * 8]);
      #pragma unroll
      for (int nt = 0; nt < 6; ++nt) {
        const int g = nt >> 1;
        if (j <= g) {
          #pragma unroll
          for (int ni = 0; ni < NI; ++ni)
            acc[ni][nt] = __builtin_amdgcn_mfma_f32_16x16x32_bf16(
                wf[bIndex(nt, j)], xf[ni], acc[ni][nt], 0, 0, 0);
        }
      }
    }
  }

  // bias: per lane 4 consecutive ch (r dim) per tile
  const float* biases[3] = {b1, b2, b3};
  float4 bv[6];
  #pragma unroll
  for (int nt = 0; nt < 6; ++nt)
    bv[nt] = *reinterpret_cast<const float4*>(
        biases[nt >> 1] + ((nt & 1) * 4 + w) * 16 + quad * 4);

  // ssq: register sums over (nt in gram, r), then 2 shfls over quads, atomic
  #pragma unroll
  for (int ni = 0; ni < NI; ++ni) {
    float p[3] = {0.f, 0.f, 0.f};
    #pragma unroll
    for (int nt = 0; nt < 6; ++nt) {
      #pragma unroll
      for (int r = 0; r < 4; ++r) {
        float y = fmaxf(acc[ni][nt][r] + bv[nt][r], 0.f);
        p[nt >> 1] += y * y;
      }
    }
    #pragma unroll
    for (int g = 0; g < 3; ++g) {
      float v = p[g];
      v += __shfl_xor(v, 16);
      v += __shfl_xor(v, 32);
      if (lane < 16) atomicAdd(&ssq[g][ni * 16 + lrow], v);
    }
  }
  __syncthreads();

  // normalize + packed dwordx2 stores (4 ch per lane)
  #pragma unroll
  for (int ni = 0; ni < NI; ++ni) {
    int l = l0 + ni * 16 + lrow;
    if (l < L) {
      float inv[3];
      #pragma unroll
      for (int g = 0; g < 3; ++g)
        inv[g] = 1.0f / (sqrtf(ssq[g][ni * 16 + lrow]) + 1e-13f);
      #pragma unroll
      for (int nt = 0; nt < 6; ++nt) {
        const int g = nt >> 1;
        unsigned int pk[2];
        #pragma unroll
        for (int h = 0; h < 2; ++h) {
          float y0 = fmaxf(acc[ni][nt][2 * h + 0] + bv[nt][2 * h + 0], 0.f) * inv[g];
          float y1 = fmaxf(acc[ni][nt][2 * h + 1] + bv[nt][2 * h + 1], 0.f) * inv[g];
          pk[h] = (unsigned int)f2bf(y0) | ((unsigned int)f2bf(y1) << 16);
        }
        unsigned short* op = out + ((size_t)(g * 128 + b) * L + l) * 128 +
                             ((nt & 1) * 4 + w) * 16 + quad * 4;
        *reinterpret_cast<uint2*>(op) = make_uint2(pk[0], pk[1]);
      }
    }
  }
}

// blocks 0..511: doc (NI=4, l0=(bi&3)*64, b=bi>>2); 512..639: query (NI=2)
__global__ __launch_bounds__(256) void conv_all(
    const float* __restrict__ qemb, const float* __restrict__ demb,
    const unsigned short* __restrict__ wt2,
    const float* __restrict__ b1, const float* __restrict__ b2,
    const float* __restrict__ b3,
    unsigned short* __restrict__ qn, unsigned short* __restrict__ dn) {
  __shared__ unsigned short As[66 * AS_STRIDE];
  __shared__ float ssq[3][64];
  const int bi = blockIdx.x;
  if (bi < 512)
    conv_body<4>(As, ssq, demb, 256, (bi & 3) * 64, bi >> 2, wt2, b1, b2, b3, dn);
  else
    conv_body<2>(As, ssq, qemb, 30, 0, bi - 512, wt2, b1, b2, b3, qn);
}

// One wave per (tg, b, dchunk of 32). A = doc rows (M=d), B = query rows
// (N=q), K = c = 128. RBF per-lane; quad shfl reduce; chunk partials out.
__global__ __launch_bounds__(64) void pool_mfma(
    const unsigned short* __restrict__ qn, const unsigned short* __restrict__ dn,
    const float* __restrict__ qmask, const float* __restrict__ dmask,
    float* __restrict__ pkq8) {
  const float MU[11] = {1.0f, 0.9f, 0.7f, 0.5f, 0.3f, 0.1f,
                        -0.1f, -0.3f, -0.5f, -0.7f, -0.9f};
  const float NEGC[11] = {-721347.52f, -72.134752f, -72.134752f, -72.134752f,
                          -72.134752f, -72.134752f, -72.134752f, -72.134752f,
                          -72.134752f, -72.134752f, -72.134752f};
  const int tg    = blockIdx.x >> 3;
  const int chunk = blockIdx.x & 7;
  const int b     = blockIdx.y;
  const int lane  = threadIdx.x;
  const int quad  = lane >> 4, l15 = lane & 15;
  const int d0    = chunk * 32;

  const unsigned short* dslab = dn + (size_t)(tg * 128 + b) * 256 * 128;

  bf16x8 aD[2][4];
  #pragma unroll
  for (int mi = 0; mi < 2; ++mi)
    #pragma unroll
    for (int kt = 0; kt < 4; ++kt)
      aD[mi][kt] = *reinterpret_cast<const bf16x8*>(
          dslab + (size_t)(d0 + mi * 16 + l15) * 128 + kt * 32 + quad * 8);

  float dmv[2][4];
  #pragma unroll
  for (int mi = 0; mi < 2; ++mi)
    #pragma unroll
    for (int r = 0; r < 4; ++r)
      dmv[mi][r] = dmask[b * 256 + d0 + mi * 16 + quad * 4 + r];

  float qmv[2];
  qmv[0] = qmask[b * 30 + l15];
  qmv[1] = (16 + l15 < 30) ? qmask[b * 30 + 16 + l15] : 0.0f;

  #pragma unroll 1
  for (int ig = 0; ig < 3; ++ig) {
    const unsigned short* qslab = qn + (size_t)(ig * 128 + b) * 30 * 128;

    bf16x8 bQ[2][4];
    #pragma unroll
    for (int ni = 0; ni < 2; ++ni)
      #pragma unroll
      for (int kt = 0; kt < 4; ++kt)
        bQ[ni][kt] = *reinterpret_cast<const bf16x8*>(
            qslab + (size_t)(ni * 16 + l15) * 128 + kt * 32 + quad * 8);

    f32x4 acc[2][2];
    #pragma unroll
    for (int mi = 0; mi < 2; ++mi)
      #pragma unroll
      for (int ni = 0; ni < 2; ++ni) acc[mi][ni] = (f32x4){0.f, 0.f, 0.f, 0.f};

    #pragma unroll
    for (int kt = 0; kt < 4; ++kt)
      #pragma unroll
      for (int mi = 0; mi < 2; ++mi)
        #pragma unroll
        for (int ni = 0; ni < 2; ++ni)
          acc[mi][ni] = __builtin_amdgcn_mfma_f32_16x16x32_bf16(
              aD[mi][kt], bQ[ni][kt], acc[mi][ni], 0, 0, 0);

    float feat[2][11];
    #pragma unroll
    for (int ni = 0; ni < 2; ++ni)
      #pragma unroll
      for (int kk = 0; kk < 11; ++kk) feat[ni][kk] = 0.0f;

    #pragma unroll
    for (int mi = 0; mi < 2; ++mi) {
      #pragma unroll
      for (int r = 0; r < 4; ++r) {
        #pragma unroll
        for (int ni = 0; ni < 2; ++ni) {
          float m  = qmv[ni] * dmv[mi][r];
          float cm = acc[mi][ni][r] * m;
          #pragma unroll
          for (int kk = 0; kk < 11; ++kk) {
            float d2 = cm - MU[kk];
            feat[ni][kk] += EXP2F(d2 * d2 * NEGC[kk]) * m;
          }
        }
      }
    }

    #pragma unroll
    for (int ni = 0; ni < 2; ++ni)
      #pragma unroll
      for (int kk = 0; kk < 11; ++kk) {
        float v = feat[ni][kk];
        v += __shfl_xor(v, 16);
        v += __shfl_xor(v, 32);
        feat[ni][kk] = v;
      }

    if (quad == 0) {
      const int pair = ig * 3 + tg;
      #pragma unroll
      for (int ni = 0; ni < 2; ++ni) {
        int q = ni * 16 + l15;
        if (q < 30) {
          float* p = pkq8 +
              (((size_t)(chunk * 9 + pair) * 128 + b) * 30 + q) * 11;
          #pragma unroll
          for (int kk = 0; kk < 11; ++kk) p[kk] = feat[ni][kk];
        }
      }
    }
  }
}

__global__ __launch_bounds__(256) void final_kernel(
    const float* __restrict__ pkq8, const float* __restrict__ qmask,
    const float* __restrict__ dw, float* __restrict__ out) {
  const int CH = 9 * 128 * 30 * 11;  // 380160
  const int b = blockIdx.x;
  const int t = threadIdx.x;
  float s = 0.0f;
  for (int idx = t; idx < 9 * 30 * 11; idx += 256) {
    int pair = idx / 330;
    int rem  = idx % 330;
    int q    = rem / 11;
    int kk   = rem % 11;
    size_t base = (((size_t)pair * 128 + b) * 30 + q) * 11 + kk;
    float v = 0.f;
    #pragma unroll
    for (int c = 0; c < 8; ++c) v += pkq8[base + (size_t)c * CH];
    s += __logf(fmaxf(v, 1e-10f)) * 0.01f * qmask[b * 30 + q] * dw[pair * 11 + kk];
  }
  s += __shfl_xor(s, 1);  s += __shfl_xor(s, 2);  s += __shfl_xor(s, 4);
  s += __shfl_xor(s, 8);  s += __shfl_xor(s, 16); s += __shfl_xor(s, 32);
  __shared__ float part[4];
  if ((t & 63) == 0) part[t >> 6] = s;
  __syncthreads();
  if (t == 0) out[b] = part[0] + part[1] + part[2] + part[3];
}

extern "C" void kernel_launch(void* const* d_in, const int* in_sizes, int n_in,
                              void* d_out, int out_size, void* d_ws, size_t ws_size,
                              hipStream_t stream) {
  const float* qemb  = (const float*)d_in[0];
  const float* demb  = (const float*)d_in[1];
  const float* qmask = (const float*)d_in[2];
  const float* dmask = (const float*)d_in[3];
  const float* w1 = (const float*)d_in[4];
  const float* b1 = (const float*)d_in[5];
  const float* w2 = (const float*)d_in[6];
  const float* b2 = (const float*)d_in[7];
  const float* w3 = (const float*)d_in[8];
  const float* b3 = (const float*)d_in[9];
  const float* dw = (const float*)d_in[10];

  unsigned short* wt2 = (unsigned short*)d_ws;       // 245760 bf16
  unsigned short* qn = wt2 + 245760;                 // 1474560 bf16
  unsigned short* dn = qn + 1474560;                 // 12582912 bf16
  float*          pkq8 = (float*)(dn + 12582912);    // 3041280 f32

  prep_w<<<960, 256, 0, stream>>>(w1, w2, w3, wt2);
  conv_all<<<640, 256, 0, stream>>>(qemb, demb, wt2, b1, b2, b3, qn, dn);
  pool_mfma<<<dim3(24, 128), 64, 0, stream>>>(qn, dn, qmask, dmask, pkq8);
  final_kernel<<<128, 256, 0, stream>>>(pkq8, qmask, dw, (float*)d_out);
}

// Round 7
// 181.200 us; speedup vs baseline: 1.1391x; 1.1391x over previous
//
#include <hip/hip_runtime.h>
#include <math.h>

// Conv-KNRM on MI355X. B=128, QLEN=30, DLEN=256, EMB=300 (pad 320), C=128.
//
// Pipeline:
//   prep_w : w fp32 -> wt2 bf16 fragment-order [plane(6)][cb(8)][ec(10)][lane(64)][8]
//   prep_x : qemb/demb fp32 -> bf16 rows [*][320] (e zero-pad; q rows 30,31 zero)
//   conv_all: uniform 32-row tiles (1152 blocks). A=w frags from global,
//             B=x rows from LDS (copy-only staging). No K-loop barriers.
//             bias+relu+L2norm, packed uint2 stores -> bf16 [g][b][l][c]
//   pool_mfma: LDS-free MFMA cos, 32-d chunks, RBF x11 -> pkq8 partials
//   final   : sum 8 chunks, log/clip/qmask/sum_q dot dense_w -> out[128]
//
// ws (shorts): wt2@0 (245760) | qx@245760 (1310720) | dx@1556480 (10485760)
//              | qn@12042240 (1474560) | dn@13516800 (12582912)  = 52.2 MB
// pkq8 (f32, 12.2 MB) aliased over qx/dx (dead after conv_all).

typedef __bf16 bf16x8 __attribute__((ext_vector_type(8)));
typedef float f32x4 __attribute__((ext_vector_type(4)));

#if __has_builtin(__builtin_amdgcn_exp2f)
#define EXP2F(x) __builtin_amdgcn_exp2f(x)
#else
#define EXP2F(x) exp2f(x)
#endif

#define AS_STRIDE 344  // shorts; 688 B row: 2-way b128 (free), 16B-aligned

static __device__ __forceinline__ unsigned short f2bf(float f) {
  union { float f; unsigned int u; } v; v.f = f;
  unsigned int r = v.u + 0x7FFFu + ((v.u >> 16) & 1u);  // RNE
  return (unsigned short)(r >> 16);
}

__global__ __launch_bounds__(256) void prep_w(
    const float* __restrict__ w1, const float* __restrict__ w2,
    const float* __restrict__ w3, unsigned short* __restrict__ wt2) {
  int idx = blockIdx.x * 256 + threadIdx.x;
  if (idx >= 245760) return;
  int jj   = idx & 7;
  int lane = (idx >> 3) & 63;
  int ec   = (idx >> 9) % 10;
  int cb   = (idx / 5120) & 7;
  int p    = idx / 40960;
  const float* w; int k, jt;
  if (p == 0)      { w = w1; k = 1; jt = 0; }
  else if (p <= 2) { w = w2; k = 2; jt = p - 1; }
  else             { w = w3; k = 3; jt = p - 3; }
  int c = cb * 16 + (lane & 15);
  int e = ec * 32 + (lane >> 4) * 8 + jj;
  float v = (e < 300) ? w[(c * 300 + e) * k + jt] : 0.0f;
  wt2[idx] = f2bf(v);
}

// rows: 4096 query (128 b x 32, rows 30/31 zero) then 32768 doc (128 x 256).
// Each thread: one 8-e chunk (uint4 out).
__global__ __launch_bounds__(256) void prep_x(
    const float* __restrict__ qemb, const float* __restrict__ demb,
    unsigned short* __restrict__ qx, unsigned short* __restrict__ dx) {
  int idx = blockIdx.x * 256 + threadIdx.x;
  if (idx >= 1474560) return;
  int c8   = idx % 40;
  int ridx = idx / 40;
  const float* src; unsigned short* dst; int valid;
  if (ridx < 4096) {
    int b = ridx >> 5, r = ridx & 31;
    valid = (r < 30);
    src = qemb + ((size_t)b * 30 + r) * 300;
    dst = qx + (size_t)ridx * 320;
  } else {
    int rd = ridx - 4096;
    valid = 1;
    src = demb + (size_t)rd * 300;
    dst = dx + (size_t)rd * 320;
  }
  int e = c8 * 8;
  float4 a = make_float4(0.f, 0.f, 0.f, 0.f);
  float4 c = make_float4(0.f, 0.f, 0.f, 0.f);
  if (valid && e < 300)     a = *reinterpret_cast<const float4*>(src + e);
  if (valid && e + 4 < 300) c = *reinterpret_cast<const float4*>(src + e + 4);
  uint4 o;
  o.x = (unsigned int)f2bf(a.x) | ((unsigned int)f2bf(a.y) << 16);
  o.y = (unsigned int)f2bf(a.z) | ((unsigned int)f2bf(a.w) << 16);
  o.z = (unsigned int)f2bf(c.x) | ((unsigned int)f2bf(c.y) << 16);
  o.w = (unsigned int)f2bf(c.z) | ((unsigned int)f2bf(c.w) << 16);
  *reinterpret_cast<uint4*>(dst + e) = o;
}

// blocks 0..1023: doc (b=bi>>3, l0=(bi&7)*32); 1024..1151: query (b=bi-1024).
// Wave tile: 32 l-rows x 96 ch (6 nt tiles; gram g=nt>>1, cb=(nt&1)*4+w).
// A-operand = weights (frag-order, global); B = x rows (LDS). D: ch=quad*4+r,
// l = ni*16 + lrow.
__global__ __launch_bounds__(256) void conv_all(
    const unsigned short* __restrict__ qx, const unsigned short* __restrict__ dx,
    const unsigned short* __restrict__ wt2,
    const float* __restrict__ b1, const float* __restrict__ b2,
    const float* __restrict__ b3,
    unsigned short* __restrict__ qn, unsigned short* __restrict__ dn) {
  __shared__ unsigned short As[34 * AS_STRIDE];
  __shared__ float psq[4][3][32];

  const int bi = blockIdx.x;
  const unsigned short* xs; unsigned short* out;
  int L, Lpad, b, l0;
  if (bi >= 1024) {
    b = bi - 1024; l0 = 0; L = 30; Lpad = 32;
    xs = qx + (size_t)b * 32 * 320; out = qn;
  } else {
    b = bi >> 3; l0 = (bi & 7) * 32; L = 256; Lpad = 256;
    xs = dx + (size_t)b * 256 * 320; out = dn;
  }

  const int t = threadIdx.x;
  const int w = __builtin_amdgcn_readfirstlane(t >> 6);
  const int lane = t & 63;
  const int quad = lane >> 4, lrow = lane & 15;

  // stage A: copy-only (already bf16), 34 rows x 40 uint4
  for (int idx = t; idx < 34 * 40; idx += 256) {
    int r = idx / 40, c = idx % 40;
    int l = l0 + r;
    uint4 v = make_uint4(0u, 0u, 0u, 0u);
    if (l < Lpad) v = *reinterpret_cast<const uint4*>(xs + (size_t)l * 320 + c * 8);
    *reinterpret_cast<uint4*>(&As[r * AS_STRIDE + c * 8]) = v;
  }
  __syncthreads();

  f32x4 acc[2][6];
  #pragma unroll
  for (int ni = 0; ni < 2; ++ni)
    #pragma unroll
    for (int nt = 0; nt < 6; ++nt) acc[ni][nt] = (f32x4){0.f, 0.f, 0.f, 0.f};

  const unsigned short* wl = wt2 + lane * 8;

  #pragma unroll 2
  for (int ec = 0; ec < 10; ++ec) {
    #pragma unroll
    for (int j = 0; j < 3; ++j) {
      bf16x8 xf[2];
      #pragma unroll
      for (int ni = 0; ni < 2; ++ni)
        xf[ni] = *reinterpret_cast<const bf16x8*>(
            &As[(ni * 16 + lrow + j) * AS_STRIDE + ec * 32 + quad * 8]);
      #pragma unroll
      for (int nt = 0; nt < 6; ++nt) {
        const int g = nt >> 1;
        if (j <= g) {
          const int cb = (nt & 1) * 4 + w;
          const int pst = (g * (g + 1)) >> 1;
          bf16x8 wf = *reinterpret_cast<const bf16x8*>(
              wl + ((((pst + j) * 8 + cb) * 10 + ec) << 9));
          acc[0][nt] = __builtin_amdgcn_mfma_f32_16x16x32_bf16(
              wf, xf[0], acc[0][nt], 0, 0, 0);
          acc[1][nt] = __builtin_amdgcn_mfma_f32_16x16x32_bf16(
              wf, xf[1], acc[1][nt], 0, 0, 0);
        }
      }
    }
  }

  const float* biases[3] = {b1, b2, b3};
  float4 bv[6];
  #pragma unroll
  for (int nt = 0; nt < 6; ++nt)
    bv[nt] = *reinterpret_cast<const float4*>(
        biases[nt >> 1] + ((nt & 1) * 4 + w) * 16 + quad * 4);

  // ssq: per-wave register sums -> 2 shfls -> per-wave LDS slot (no atomics)
  #pragma unroll
  for (int ni = 0; ni < 2; ++ni) {
    float p[3] = {0.f, 0.f, 0.f};
    #pragma unroll
    for (int nt = 0; nt < 6; ++nt) {
      #pragma unroll
      for (int r = 0; r < 4; ++r) {
        float y = fmaxf(acc[ni][nt][r] + bv[nt][r], 0.f);
        p[nt >> 1] += y * y;
      }
    }
    #pragma unroll
    for (int g = 0; g < 3; ++g) {
      float v = p[g];
      v += __shfl_xor(v, 16);
      v += __shfl_xor(v, 32);
      if (lane < 16) psq[w][g][ni * 16 + lrow] = v;
    }
  }
  __syncthreads();

  #pragma unroll
  for (int ni = 0; ni < 2; ++ni) {
    int row = ni * 16 + lrow;
    int l = l0 + row;
    if (l < L) {
      float inv[3];
      #pragma unroll
      for (int g = 0; g < 3; ++g)
        inv[g] = 1.0f / (sqrtf(psq[0][g][row] + psq[1][g][row] +
                               psq[2][g][row] + psq[3][g][row]) + 1e-13f);
      #pragma unroll
      for (int nt = 0; nt < 6; ++nt) {
        const int g = nt >> 1;
        unsigned int pk[2];
        #pragma unroll
        for (int h = 0; h < 2; ++h) {
          float y0 = fmaxf(acc[ni][nt][2 * h + 0] + bv[nt][2 * h + 0], 0.f) * inv[g];
          float y1 = fmaxf(acc[ni][nt][2 * h + 1] + bv[nt][2 * h + 1], 0.f) * inv[g];
          pk[h] = (unsigned int)f2bf(y0) | ((unsigned int)f2bf(y1) << 16);
        }
        unsigned short* op = out + ((size_t)(g * 128 + b) * L + l) * 128 +
                             ((nt & 1) * 4 + w) * 16 + quad * 4;
        *reinterpret_cast<uint2*>(op) = make_uint2(pk[0], pk[1]);
      }
    }
  }
}

// One wave per (tg, b, dchunk of 32). A = doc rows (M=d), B = query rows
// (N=q), K = c = 128. RBF per-lane; quad shfl reduce; chunk partials out.
__global__ __launch_bounds__(64) void pool_mfma(
    const unsigned short* __restrict__ qn, const unsigned short* __restrict__ dn,
    const float* __restrict__ qmask, const float* __restrict__ dmask,
    float* __restrict__ pkq8) {
  const float MU[11] = {1.0f, 0.9f, 0.7f, 0.5f, 0.3f, 0.1f,
                        -0.1f, -0.3f, -0.5f, -0.7f, -0.9f};
  const float NEGC[11] = {-721347.52f, -72.134752f, -72.134752f, -72.134752f,
                          -72.134752f, -72.134752f, -72.134752f, -72.134752f,
                          -72.134752f, -72.134752f, -72.134752f};
  const int tg    = blockIdx.x >> 3;
  const int chunk = blockIdx.x & 7;
  const int b     = blockIdx.y;
  const int lane  = threadIdx.x;
  const int quad  = lane >> 4, l15 = lane & 15;
  const int d0    = chunk * 32;

  const unsigned short* dslab = dn + (size_t)(tg * 128 + b) * 256 * 128;

  bf16x8 aD[2][4];
  #pragma unroll
  for (int mi = 0; mi < 2; ++mi)
    #pragma unroll
    for (int kt = 0; kt < 4; ++kt)
      aD[mi][kt] = *reinterpret_cast<const bf16x8*>(
          dslab + (size_t)(d0 + mi * 16 + l15) * 128 + kt * 32 + quad * 8);

  float dmv[2][4];
  #pragma unroll
  for (int mi = 0; mi < 2; ++mi)
    #pragma unroll
    for (int r = 0; r < 4; ++r)
      dmv[mi][r] = dmask[b * 256 + d0 + mi * 16 + quad * 4 + r];

  float qmv[2];
  qmv[0] = qmask[b * 30 + l15];
  qmv[1] = (16 + l15 < 30) ? qmask[b * 30 + 16 + l15] : 0.0f;

  #pragma unroll 1
  for (int ig = 0; ig < 3; ++ig) {
    const unsigned short* qslab = qn + (size_t)(ig * 128 + b) * 30 * 128;

    bf16x8 bQ[2][4];
    #pragma unroll
    for (int ni = 0; ni < 2; ++ni)
      #pragma unroll
      for (int kt = 0; kt < 4; ++kt)
        bQ[ni][kt] = *reinterpret_cast<const bf16x8*>(
            qslab + (size_t)(ni * 16 + l15) * 128 + kt * 32 + quad * 8);

    f32x4 acc[2][2];
    #pragma unroll
    for (int mi = 0; mi < 2; ++mi)
      #pragma unroll
      for (int ni = 0; ni < 2; ++ni) acc[mi][ni] = (f32x4){0.f, 0.f, 0.f, 0.f};

    #pragma unroll
    for (int kt = 0; kt < 4; ++kt)
      #pragma unroll
      for (int mi = 0; mi < 2; ++mi)
        #pragma unroll
        for (int ni = 0; ni < 2; ++ni)
          acc[mi][ni] = __builtin_amdgcn_mfma_f32_16x16x32_bf16(
              aD[mi][kt], bQ[ni][kt], acc[mi][ni], 0, 0, 0);

    float feat[2][11];
    #pragma unroll
    for (int ni = 0; ni < 2; ++ni)
      #pragma unroll
      for (int kk = 0; kk < 11; ++kk) feat[ni][kk] = 0.0f;

    #pragma unroll
    for (int mi = 0; mi < 2; ++mi) {
      #pragma unroll
      for (int r = 0; r < 4; ++r) {
        #pragma unroll
        for (int ni = 0; ni < 2; ++ni) {
          float m  = qmv[ni] * dmv[mi][r];
          float cm = acc[mi][ni][r] * m;
          #pragma unroll
          for (int kk = 0; kk < 11; ++kk) {
            float d2 = cm - MU[kk];
            feat[ni][kk] += EXP2F(d2 * d2 * NEGC[kk]) * m;
          }
        }
      }
    }

    #pragma unroll
    for (int ni = 0; ni < 2; ++ni)
      #pragma unroll
      for (int kk = 0; kk < 11; ++kk) {
        float v = feat[ni][kk];
        v += __shfl_xor(v, 16);
        v += __shfl_xor(v, 32);
        feat[ni][kk] = v;
      }

    if (quad == 0) {
      const int pair = ig * 3 + tg;
      #pragma unroll
      for (int ni = 0; ni < 2; ++ni) {
        int q = ni * 16 + l15;
        if (q < 30) {
          float* p = pkq8 +
              (((size_t)(chunk * 9 + pair) * 128 + b) * 30 + q) * 11;
          #pragma unroll
          for (int kk = 0; kk < 11; ++kk) p[kk] = feat[ni][kk];
        }
      }
    }
  }
}

__global__ __launch_bounds__(256) void final_kernel(
    const float* __restrict__ pkq8, const float* __restrict__ qmask,
    const float* __restrict__ dw, float* __restrict__ out) {
  const int CH = 9 * 128 * 30 * 11;  // 380160
  const int b = blockIdx.x;
  const int t = threadIdx.x;
  float s = 0.0f;
  for (int idx = t; idx < 9 * 30 * 11; idx += 256) {
    int pair = idx / 330;
    int rem  = idx % 330;
    int q    = rem / 11;
    int kk   = rem % 11;
    size_t base = (((size_t)pair * 128 + b) * 30 + q) * 11 + kk;
    float v = 0.f;
    #pragma unroll
    for (int c = 0; c < 8; ++c) v += pkq8[base + (size_t)c * CH];
    s += __logf(fmaxf(v, 1e-10f)) * 0.01f * qmask[b * 30 + q] * dw[pair * 11 + kk];
  }
  s += __shfl_xor(s, 1);  s += __shfl_xor(s, 2);  s += __shfl_xor(s, 4);
  s += __shfl_xor(s, 8);  s += __shfl_xor(s, 16); s += __shfl_xor(s, 32);
  __shared__ float part[4];
  if ((t & 63) == 0) part[t >> 6] = s;
  __syncthreads();
  if (t == 0) out[b] = part[0] + part[1] + part[2] + part[3];
}

extern "C" void kernel_launch(void* const* d_in, const int* in_sizes, int n_in,
                              void* d_out, int out_size, void* d_ws, size_t ws_size,
                              hipStream_t stream) {
  const float* qemb  = (const float*)d_in[0];
  const float* demb  = (const float*)d_in[1];
  const float* qmask = (const float*)d_in[2];
  const float* dmask = (const float*)d_in[3];
  const float* w1 = (const float*)d_in[4];
  const float* b1 = (const float*)d_in[5];
  const float* w2 = (const float*)d_in[6];
  const float* b2 = (const float*)d_in[7];
  const float* w3 = (const float*)d_in[8];
  const float* b3 = (const float*)d_in[9];
  const float* dw = (const float*)d_in[10];

  unsigned short* ws   = (unsigned short*)d_ws;
  unsigned short* wt2  = ws;                    // 245760
  unsigned short* qx   = ws + 245760;           // 1310720
  unsigned short* dx   = ws + 1556480;          // 10485760
  unsigned short* qn   = ws + 12042240;         // 1474560
  unsigned short* dn   = ws + 13516800;         // 12582912
  float*          pkq8 = (float*)(ws + 245760); // aliased over qx/dx (dead)

  prep_w<<<960, 256, 0, stream>>>(w1, w2, w3, wt2);
  prep_x<<<5760, 256, 0, stream>>>(qemb, demb, qx, dx);
  conv_all<<<1152, 256, 0, stream>>>(qx, dx, wt2, b1, b2, b3, qn, dn);
  pool_mfma<<<dim3(24, 128), 64, 0, stream>>>(qn, dn, qmask, dmask, pkq8);
  final_kernel<<<128, 256, 0, stream>>>(pkq8, qmask, dw, (float*)d_out);
}